// Round 14
// baseline (256.635 us; speedup 1.0000x reference)
//
#include <hip/hip_runtime.h>
#include <hip/hip_bf16.h>
#include <math.h>

typedef unsigned short u16;
typedef unsigned int u32;
typedef __attribute__((ext_vector_type(4))) float f32x4;
typedef __attribute__((ext_vector_type(8))) short s16x8;
typedef __attribute__((ext_vector_type(8))) unsigned short u16x8;

#define DEV __device__ __forceinline__

// Problem dims: V=32000, E=1024, H=1024, A=1024, B=64, S=512

DEV u16 f2bf(float f) {
    union { float f; u32 u; } x{f};
    return (u16)((x.u + 0x7FFFu + ((x.u >> 16) & 1u)) >> 16);
}
DEV float bf2f(u16 h) {
    union { u32 u; float f; } x;
    x.u = ((u32)h) << 16;
    return x.f;
}
DEV float sigm(float x) { return 1.0f / (1.0f + __expf(-x)); }
DEV float tanh_f(float x) {
    float c = fminf(fmaxf(x, -9.0f), 9.0f);
    float e = __expf(2.0f * c);
    return (e - 1.0f) / (e + 1.0f);
}

// async global->LDS, 16B per lane (dest = wave-uniform base + lane*16)
#define GLL16(g, l) __builtin_amdgcn_global_load_lds( \
    (const __attribute__((address_space(1))) u32*)(g), \
    (__attribute__((address_space(3))) u32*)(l), 16, 0, 0)

// ------------------------- fused prep: cvt enc + zero scores + cvt Ua + h0
__global__ __launch_bounds__(256) void kprepcvt(
    const float* __restrict__ enc, const float* __restrict__ Ua,
    const float* __restrict__ h0, u16* __restrict__ encbf,
    u16* __restrict__ Uabf, u16* __restrict__ h0bf, float* __restrict__ scores)
{
    int bid = blockIdx.x, t = threadIdx.x;
    if (bid < 16384) {
        int i = bid * 256 + t;             // enc: 4194304 groups of 8
        float4 f0 = ((const float4*)enc)[i * 2];
        float4 f1 = ((const float4*)enc)[i * 2 + 1];
        u16x8 o = {f2bf(f0.x), f2bf(f0.y), f2bf(f0.z), f2bf(f0.w),
                   f2bf(f1.x), f2bf(f1.y), f2bf(f1.z), f2bf(f1.w)};
        ((u16x8*)encbf)[i] = o;
    } else if (bid < 16400) {
        int i = (bid - 16384) * 2048 + t * 8;   // scores zero (32768 f32)
        *(float4*)(scores + i) = (float4){0.f, 0.f, 0.f, 0.f};
        *(float4*)(scores + i + 4) = (float4){0.f, 0.f, 0.f, 0.f};
    } else if (bid < 16912) {
        int i = (bid - 16400) * 256 + t;   // Ua: 131072 groups of 8
        float4 f0 = ((const float4*)Ua)[i * 2];
        float4 f1 = ((const float4*)Ua)[i * 2 + 1];
        u16x8 o = {f2bf(f0.x), f2bf(f0.y), f2bf(f0.z), f2bf(f0.w),
                   f2bf(f1.x), f2bf(f1.y), f2bf(f1.z), f2bf(f1.w)};
        ((u16x8*)Uabf)[i] = o;
    } else {
        int i = (bid - 16912) * 256 + t;   // h0: 8192 groups of 8
        float4 f0 = ((const float4*)h0)[i * 2];
        float4 f1 = ((const float4*)h0)[i * 2 + 1];
        u16x8 o = {f2bf(f0.x), f2bf(f0.y), f2bf(f0.z), f2bf(f0.w),
                   f2bf(f1.x), f2bf(f1.y), f2bf(f1.z), f2bf(f1.w)};
        ((u16x8*)h0bf)[i] = o;
    }
}

// ------------------------------------------------- scores GEMM (the big one)
// scores[m] = sum_a va[a]*tanh(tmp1c[m&63][a] + sum_h enc[m,h]*Ua[a,h])
// M=32768, N=1024, K=1024 bf16.  256x256 tile, BK=64, 512 thr (2M x 4N).
// R14: A-only LDS (2 slots x 32KB, GLL16 + XOR swizzle); B (Ua, L2-resident)
// read DIRECTLY global->registers in natural layout — removes 1/3 of
// ds_read_b128 traffic (the measured co-limiter) and one barrier per tile.
// Ledger: r0/r128 of a slot dead after ph1 -> restaged (T+2) at ph2 after
// ph1-bar; r64/r192 dead after ph3 -> staged (T+1) at next ph0 after ph3-bar.
// vmcnt(2) at ph3 covers r64/r192(T+1) (2 newer = r0/r128(T+2)); B loads
// pinned to ph0 by sched_barrier so the FIFO count holds.

template<int F0>
DEV void mmq(f32x4 (&acc)[8][4], const s16x8 (&af)[2][2], const s16x8 (&bfrag)[4][2]) {
#pragma unroll
    for (int f = 0; f < 2; f++)
#pragma unroll
        for (int j = 0; j < 4; j++) {
            acc[F0 + f][j] = __builtin_amdgcn_mfma_f32_16x16x32_bf16(af[f][0], bfrag[j][0], acc[F0 + f][j], 0, 0, 0);
            acc[F0 + f][j] = __builtin_amdgcn_mfma_f32_16x16x32_bf16(af[f][1], bfrag[j][1], acc[F0 + f][j], 0, 0, 0);
        }
}

__global__ __launch_bounds__(512, 1) void kscores256v3(
    const u16* __restrict__ encbf, const u16* __restrict__ Uabf,
    const float* __restrict__ tmp1c, const float* __restrict__ va,
    float* __restrict__ scores)
{
    // A slots at elems 0 / 16384 (32KB each); epilogue overlays f32[64][260].
    __shared__ __align__(16) u16 shm[33280];   // 66560 B

    // XCD swizzle: 512 blocks / 8 XCDs -> 16 consecutive mt per XCD.
    int wg  = blockIdx.x;
    int lin = (wg & 7) * 64 + (wg >> 3);
    int mt  = lin >> 2, nt = lin & 3;   // mt 0..127, nt 0..3

    int t = threadIdx.x;
    int wid = t >> 6, lane = t & 63;
    int wm = wid >> 2, wn = wid & 3;    // 2M x 4N waves; per-wave out 128x64
    int lr = lane & 15, lg = lane >> 4;

    f32x4 acc[8][4];
#pragma unroll
    for (int i = 0; i < 8; i++)
#pragma unroll
        for (int j = 0; j < 4; j++) acc[i][j] = (f32x4){0.f, 0.f, 0.f, 0.f};

    // A staging: one GLL16 line = 512 thr x 16B = 64 rows x 128B
    int srow = t >> 3;
    int sq8  = ((t & 7) ^ (srow & 7)) * 8;      // pre-swizzled source offset
    const u16* asrcb = encbf + (size_t)(mt * 256 + srow) * 1024 + sq8;

#define STG_A(SE, RB, KO) GLL16(asrcb + (size_t)(RB) * 1024 + (KO), shm + (SE) + (RB) * 64 + t * 8)

    // A read base; swizzle inverse on read: q_read = q_want ^ (lr&7)
    const u16* Abase = shm + (wm * 128 + lr) * 64;
    int xor8 = (lr & 7) * 8;
    int o0 = (lg * 8) ^ xor8;            // ks=0
    int o1 = (32 + lg * 8) ^ xor8;       // ks=1

    // B direct-global base: lane (lr,lg) of wave wn covers row wn*64+j*16+lr,
    // k = k0 + ks*32 + lg*8  (natural layout, 16 rows x 64B per instr)
    const u16* browbase = Uabf + (size_t)(nt * 256 + wn * 64 + lr) * 1024 + lg * 8;

    s16x8 af[2][2], bfrag[4][2];

#define RD_A2(F0, AB) { \
    af[0][0] = *(const s16x8*)((AB) + (F0) * 1024 + o0); \
    af[0][1] = *(const s16x8*)((AB) + (F0) * 1024 + o1); \
    af[1][0] = *(const s16x8*)((AB) + (F0 + 1) * 1024 + o0); \
    af[1][1] = *(const s16x8*)((AB) + (F0 + 1) * 1024 + o1); }

#define LD_B(KT) { \
    const u16* bp = browbase + (KT); \
    _Pragma("unroll") \
    for (int j = 0; j < 4; j++) { \
        bfrag[j][0] = *(const s16x8*)(bp + (size_t)j * 16384); \
        bfrag[j][1] = *(const s16x8*)(bp + (size_t)j * 16384 + 32); \
    } \
}

#define MM(F0) \
    __builtin_amdgcn_s_setprio(1); \
    mmq<F0>(acc, af, bfrag); \
    __builtin_amdgcn_s_setprio(0);

#define BAR() \
    __builtin_amdgcn_s_barrier(); \
    __builtin_amdgcn_sched_barrier(0);

    // prologue: tile0 fully + tile1 r0/r128 (matches steady-state FIFO)
    STG_A(0, 0, 0); STG_A(0, 128, 0); STG_A(0, 64, 0); STG_A(0, 192, 0);
    STG_A(16384, 0, 64); STG_A(16384, 128, 64);
    asm volatile("s_waitcnt vmcnt(2)" ::: "memory");   // tile0's 4 landed
    BAR();

// SAH: stage A r64/r192(T+1) at ph0; STP2: stage A r0/r128(T+2) at ph2;
// WC: 2 = counted, 0 = full drain (tail), -1 = none.
#define TILE_BODY(T, SB, SBX, SAH, STP2, WC) { \
    int kT = (T) * 64; \
    const u16* Ab = Abase + (SB); \
    /* ph0: B(T) loads (pinned), stage A r64/r192(T+1) -> other slot, fi0,1 */ \
    LD_B(kT); \
    __builtin_amdgcn_sched_barrier(0); \
    if (SAH) { STG_A((SBX), 64, kT + 64); STG_A((SBX), 192, kT + 64); } \
    RD_A2(0, Ab); \
    MM(0); \
    __builtin_amdgcn_sched_barrier(0); \
    /* ph1: fi2,3 (finishes r0/r128 reads of this slot) */ \
    RD_A2(2, Ab); \
    MM(2); \
    BAR();                      /* r0/r128 reads complete everywhere */ \
    /* ph2: stage A r0/r128(T+2) -> this slot; fi4,5 */ \
    if (STP2) { STG_A((SB), 0, kT + 128); STG_A((SB), 128, kT + 128); } \
    RD_A2(4, Ab); \
    MM(4); \
    __builtin_amdgcn_sched_barrier(0); \
    /* ph3: fi6,7; tile-swap guard */ \
    RD_A2(6, Ab); \
    if ((WC) == 2) { asm volatile("s_waitcnt vmcnt(2)" ::: "memory"); } \
    else if ((WC) == 0) { asm volatile("s_waitcnt vmcnt(0)" ::: "memory"); } \
    MM(6); \
    BAR();                      /* tile T+1 fully landed for next ph0 */ \
}

    for (int tt = 0; tt < 7; tt++) {
        int T0 = tt * 2;
        TILE_BODY(T0, 0, 16384, 1, 1, 2);
        TILE_BODY(T0 + 1, 16384, 0, 1, 1, 2);
    }
    // tail: T=14 stages only r64/r192(15) at ph0 then drains; T=15 pure
    TILE_BODY(14, 0, 16384, 1, 0, 0);
    TILE_BODY(15, 16384, 0, 0, 0, -1);

    // drain (nothing should be outstanding) + reuse LDS for epilogue
    asm volatile("s_waitcnt vmcnt(0)" ::: "memory");
    __builtin_amdgcn_s_barrier();
    __builtin_amdgcn_sched_barrier(0);

    // stage tmp1c slice [64 b][256 a] into LDS, padded stride 260 f32
    float* ltmp = (float*)shm;
#pragma unroll
    for (int i = 0; i < 8; i++) {
        int idx = t + i * 512;              // 0..4095
        int row = idx >> 6, c4 = idx & 63;
        float4 v = *(const float4*)(tmp1c + row * 1024 + nt * 256 + c4 * 4);
        *(float4*)(ltmp + row * 260 + c4 * 4) = v;
    }
    __syncthreads();

    // Epilogue: val = va[a]*tanh(acc + tmp1[b][a]); reduce over this block's
    // 256 cols (4 n-waves x 64), atomicAdd per-row partial into scores.
    float vaj[4];
#pragma unroll
    for (int j = 0; j < 4; j++) vaj[j] = va[nt * 256 + wn * 64 + j * 16 + lr];

#pragma unroll
    for (int fi = 0; fi < 8; fi++) {
        float rs[4] = {0.f, 0.f, 0.f, 0.f};
#pragma unroll
        for (int j = 0; j < 4; j++) {
            int ac = wn * 64 + j * 16 + lr;
#pragma unroll
            for (int r = 0; r < 4; r++) {
                int b = (fi * 16 + lg * 4 + r) & 63;
                rs[r] += vaj[j] * tanh_f(acc[fi][j][r] + ltmp[b * 260 + ac]);
            }
        }
#pragma unroll
        for (int m = 1; m < 16; m <<= 1)
#pragma unroll
            for (int r = 0; r < 4; r++) rs[r] += __shfl_xor(rs[r], m, 64);
        if (lr == 0) {
            int mrow = mt * 256 + wm * 128 + fi * 16 + lg * 4;
#pragma unroll
            for (int r = 0; r < 4; r++) atomicAdd(&scores[mrow + r], rs[r]);
        }
    }
#undef STG_A
#undef RD_A2
#undef LD_B
#undef MM
#undef BAR
#undef TILE_BODY
}

// -------------------------------------- skinny GEMM: C = Abf(64xK) * B^T
// B is fp32 [N][K] split as [B1 (K1 cols) | B2 (K-K1 cols)], converted on the
// fly. Grid: (N/128, KS). Each block: 64x128 tile, 4 waves of 64x32.
__global__ __launch_bounds__(256) void kskinny(
    const u16* __restrict__ Abf, int Ktot,
    const float* __restrict__ B1, int K1,
    const float* __restrict__ B2,
    float* __restrict__ Cout, int N, int klen)
{
    __shared__ u16 As[64 * 40];
    __shared__ u16 Bs[128 * 40];

    int nt = blockIdx.x, p = blockIdx.y;
    int t = threadIdx.x;
    int wid = t >> 6, lane = t & 63;
    int lr = lane & 15, lg = lane >> 4;
    int K2 = Ktot - K1;

    f32x4 acc[4][2];
#pragma unroll
    for (int i = 0; i < 4; i++)
#pragma unroll
        for (int j = 0; j < 2; j++) acc[i][j] = (f32x4){0.f, 0.f, 0.f, 0.f};

    int arow = t >> 2, aq = t & 3;
    const u16* ap = Abf + (size_t)arow * Ktot + aq * 8;
    u16* asw = &As[arow * 40 + aq * 8];

    int brow = t >> 1, bhalf = t & 1;
    int n = nt * 128 + brow;
    u16* bsw = &Bs[brow * 40 + bhalf * 16];

    int kbeg = p * klen, kend = kbeg + klen;
    for (int k0 = kbeg; k0 < kend; k0 += 32) {
        __syncthreads();
        *(uint4*)asw = *(const uint4*)(ap + k0);
        int kk = k0 + bhalf * 16;
        const float* bp = (kk < K1) ? (B1 + (size_t)n * K1 + kk)
                                    : (B2 + (size_t)n * K2 + (kk - K1));
        float4 b0 = ((const float4*)bp)[0];
        float4 b1 = ((const float4*)bp)[1];
        float4 b2 = ((const float4*)bp)[2];
        float4 b3 = ((const float4*)bp)[3];
        u16x8 q0 = {f2bf(b0.x), f2bf(b0.y), f2bf(b0.z), f2bf(b0.w),
                    f2bf(b1.x), f2bf(b1.y), f2bf(b1.z), f2bf(b1.w)};
        u16x8 q1 = {f2bf(b2.x), f2bf(b2.y), f2bf(b2.z), f2bf(b2.w),
                    f2bf(b3.x), f2bf(b3.y), f2bf(b3.z), f2bf(b3.w)};
        *(u16x8*)bsw = q0;
        *(u16x8*)(bsw + 8) = q1;
        __syncthreads();

        const u16* abase = &As[lr * 40 + lg * 8];
        const u16* bbase = &Bs[(wid * 32 + lr) * 40 + lg * 8];
        s16x8 af[4], bfr[2];
#pragma unroll
        for (int i = 0; i < 4; i++) af[i]  = *(const s16x8*)(abase + i * 16 * 40);
#pragma unroll
        for (int j = 0; j < 2; j++) bfr[j] = *(const s16x8*)(bbase + j * 16 * 40);
#pragma unroll
        for (int i = 0; i < 4; i++)
#pragma unroll
            for (int j = 0; j < 2; j++)
                acc[i][j] = __builtin_amdgcn_mfma_f32_16x16x32_bf16(af[i], bfr[j], acc[i][j], 0, 0, 0);
    }

#pragma unroll
    for (int i = 0; i < 4; i++)
#pragma unroll
        for (int j = 0; j < 2; j++) {
            int m = i * 16 + lg * 4;
            int col = nt * 128 + wid * 32 + j * 16 + lr;
#pragma unroll
            for (int r = 0; r < 4; r++)
                Cout[((size_t)(p * 64 + m + r)) * N + col] = acc[i][j][r];
        }
}

// --------------------------------------------- reduce K-splits + add biases
__global__ void kredbias(const float* __restrict__ part, const float* __restrict__ bias1,
                         const float* __restrict__ bias2, float* __restrict__ out,
                         int N, int P)
{
    int idx = blockIdx.x * blockDim.x + threadIdx.x;
    if (idx >= 64 * N) return;
    int n = idx % N;
    float v = bias1[n] + bias2[n];
    for (int p = 0; p < P; p++) v += part[(size_t)p * 64 * N + idx];
    out[idx] = v;
}

// ---------------- ctx partial with fused softmax: 8 s-chunks x 64 b blocks
// Each block recomputes the softmax over S for its b column (2 KB, L2-hot),
// then does its chunk's weighted encoder sum — removes ksoftmax_w + wbuf.
__global__ __launch_bounds__(256) void kctx(const u16* __restrict__ encbf,
                                            const float* __restrict__ scores,
                                            float* __restrict__ pctx)
{
    int b = blockIdx.x & 63, ch = blockIdx.x >> 6;
    int t = threadIdx.x;
    int lane = t & 63, wv = t >> 6;
    __shared__ float redm[4], reds[4];
    __shared__ float wch[64];

    float v0 = scores[(2 * t) * 64 + b];
    float v1 = scores[(2 * t + 1) * 64 + b];
    float m = fmaxf(v0, v1);
#pragma unroll
    for (int mask = 1; mask < 64; mask <<= 1) m = fmaxf(m, __shfl_xor(m, mask, 64));
    if (lane == 0) redm[wv] = m;
    __syncthreads();
    m = fmaxf(fmaxf(redm[0], redm[1]), fmaxf(redm[2], redm[3]));
    float e0 = __expf(v0 - m), e1 = __expf(v1 - m);
    float sum = e0 + e1;
#pragma unroll
    for (int mask = 1; mask < 64; mask <<= 1) sum += __shfl_xor(sum, mask, 64);
    if (lane == 0) reds[wv] = sum;
    __syncthreads();
    sum = (reds[0] + reds[1]) + (reds[2] + reds[3]);
    float inv = 1.0f / sum;
    int base = ch * 32;
    if (t >= base && t < base + 32) {
        wch[2 * (t - base)]     = e0 * inv;
        wch[2 * (t - base) + 1] = e1 * inv;
    }
    __syncthreads();

    float4 acc = {0.f, 0.f, 0.f, 0.f};
    int s0 = ch * 64;
#pragma unroll 4
    for (int si = 0; si < 64; si++) {
        int s = s0 + si;
        float wv2 = wch[si];
        ushort4 e = ((const ushort4*)(encbf + ((size_t)(s * 64 + b)) * 1024))[t];
        acc.x += wv2 * bf2f(e.x); acc.y += wv2 * bf2f(e.y);
        acc.z += wv2 * bf2f(e.z); acc.w += wv2 * bf2f(e.w);
    }
    ((float4*)pctx)[((size_t)(ch * 64 + b)) * 256 + t] = acc;
}

// ---------------------- assemble LSTM input [emb[x] | ctx | h0] as bf16 rows
__global__ void kbuild(const int* __restrict__ x, const float* __restrict__ emb,
                       const float* __restrict__ pctx, const float* __restrict__ h0,
                       u16* __restrict__ inp2bf)
{
    int idx = blockIdx.x * blockDim.x + threadIdx.x;
    if (idx >= 64 * 3072) return;
    int b = idx / 3072, k = idx % 3072;
    float v;
    if (k < 1024) {
        v = emb[(size_t)x[b] * 1024 + k];
    } else if (k < 2048) {
        int h = k - 1024;
        v = 0.f;
        for (int p = 0; p < 8; p++) v += pctx[(size_t)(p * 64 + b) * 1024 + h];
    } else {
        v = h0[b * 1024 + (k - 2048)];
    }
    inp2bf[idx] = f2bf(v);
}

// --------------------------------------- reduce gate K-splits + LSTM step
__global__ void klstm(const float* __restrict__ gp, const float* __restrict__ b_ih,
                      const float* __restrict__ b_hh, const float* __restrict__ c0,
                      u16* __restrict__ h1bf)
{
    int idx = blockIdx.x * blockDim.x + threadIdx.x;  // 64*1024
    int b = idx >> 10, j = idx & 1023;
    float ig = b_ih[j] + b_hh[j];
    float fg = b_ih[1024 + j] + b_hh[1024 + j];
    float gg = b_ih[2048 + j] + b_hh[2048 + j];
    float og = b_ih[3072 + j] + b_hh[3072 + j];
    for (int p = 0; p < 8; p++) {
        const float* g = gp + ((size_t)p * 64 + b) * 4096;
        ig += g[j]; fg += g[1024 + j]; gg += g[2048 + j]; og += g[3072 + j];
    }
    float c = sigm(fg) * c0[idx] + sigm(ig) * tanh_f(gg);
    float h = sigm(og) * tanh_f(c);
    h1bf[idx] = f2bf(h);
}

// --------------- log-softmax (sums 2 logits K-split partials)
__global__ __launch_bounds__(1024) void klogsoftmax(const float* __restrict__ lp,
                                                    const float* __restrict__ b_clf,
                                                    float* __restrict__ out)
{
    int b = blockIdx.x, t = threadIdx.x;
    __shared__ float red[16], red2[16];
    float v[32];
    float mx = -1e30f;
#pragma unroll
    for (int i = 0; i < 32; i++) {
        int idx = t + i * 1024;
        if (idx < 32000) {
            float s = b_clf[idx];
#pragma unroll
            for (int p = 0; p < 2; p++)
                s += lp[((size_t)(p * 64 + b)) * 32000 + idx];
            v[i] = s;
            mx = fmaxf(mx, v[i]);
        } else v[i] = -1e30f;
    }
#pragma unroll
    for (int mask = 1; mask < 64; mask <<= 1) mx = fmaxf(mx, __shfl_xor(mx, mask, 64));
    if ((t & 63) == 0) red[t >> 6] = mx;
    __syncthreads();
#pragma unroll
    for (int k = 0; k < 16; k++) mx = fmaxf(mx, red[k]);
    float s = 0.f;
#pragma unroll
    for (int i = 0; i < 32; i++) {
        int idx = t + i * 1024;
        if (idx < 32000) s += __expf(v[i] - mx);
    }
#pragma unroll
    for (int mask = 1; mask < 64; mask <<= 1) s += __shfl_xor(s, mask, 64);
    if ((t & 63) == 0) red2[t >> 6] = s;
    __syncthreads();
    s = 0.f;
#pragma unroll
    for (int k = 0; k < 16; k++) s += red2[k];
    float lse = mx + logf(s);
#pragma unroll
    for (int i = 0; i < 32; i++) {
        int idx = t + i * 1024;
        if (idx < 32000) out[(size_t)b * 32000 + idx] = v[i] - lse;
    }
}

// =========================================================================
extern "C" void kernel_launch(void* const* d_in, const int* in_sizes, int n_in,
                              void* d_out, int out_size, void* d_ws, size_t ws_size,
                              hipStream_t stream)
{
    const int*   x     = (const int*)d_in[0];
    const float* enc   = (const float*)d_in[1];
    const float* h0    = (const float*)d_in[2];
    const float* c0    = (const float*)d_in[3];
    const float* Wa    = (const float*)d_in[4];
    const float* b_wa  = (const float*)d_in[5];
    const float* Ua    = (const float*)d_in[6];
    const float* b_ua  = (const float*)d_in[7];
    const float* va    = (const float*)d_in[8];
    // d_in[9] = b_va: constant shift, cancels in softmax over S -> unused
    const float* emb   = (const float*)d_in[10];
    const float* W_ih  = (const float*)d_in[11];
    const float* W_hh  = (const float*)d_in[12];
    const float* b_ih  = (const float*)d_in[13];
    const float* b_hh  = (const float*)d_in[14];
    const float* W_clf = (const float*)d_in[15];
    const float* b_clf = (const float*)d_in[16];
    float* out = (float*)d_out;

    char* ws = (char*)d_ws;
    // encbf occupies [0, 64MB); gparts/lparts overlay it (used only after
    // kctx, the last encbf reader — launches are stream-ordered).
    u16*   encbf    = (u16*)  (ws + 0);           // 33.5M bf16 (64 MB)
    float* gparts   = (float*)(ws + 0);           // 8*64*4096 f32 (8 MB)
    float* lparts   = (float*)(ws + 8388608);     // 2*64*32000 f32 (16.4 MB)
    float* scores   = (float*)(ws + 67108864);    // 32768 f32
    float* tmp1part = (float*)(ws + 67371008);    // 8*64*1024 f32 (2 MB)
    float* tmp1c    = (float*)(ws + 69468160);    // 64*1024 f32 (256 KB)
    u16*   h0bf     = (u16*)  (ws + 69730304);    // 64*1024 bf16 (128 KB)
    u16*   Uabf     = (u16*)  (ws + 69861376);    // 1M bf16 (2 MB)
    float* pctx     = (float*)(ws + 71958528);    // 8*64*1024 f32 (2 MB)
    u16*   inp2bf   = (u16*)  (ws + 74055680);    // 64*3072 bf16 (384 KB)
    u16*   h1bf     = (u16*)  (ws + 74448896);    // 64*1024 bf16 (128 KB)
    // total ~74.6 MB

    kprepcvt<<<16944, 256, 0, stream>>>(enc, Ua, h0, encbf, Uabf, h0bf, scores);

    // tmp1[b][a] = h0 . Wa[a]  (+ b_wa + b_ua in reduce)
    {
        dim3 g(8, 8);
        kskinny<<<g, 256, 0, stream>>>(h0bf, 1024, Wa, 1024, nullptr, tmp1part, 1024, 128);
    }
    kredbias<<<256, 256, 0, stream>>>(tmp1part, b_wa, b_ua, tmp1c, 1024, 8);

    kscores256v3<<<512, 512, 0, stream>>>(encbf, Uabf, tmp1c, va, scores);
    kctx<<<512, 256, 0, stream>>>(encbf, scores, pctx);
    kbuild<<<768, 256, 0, stream>>>(x, emb, pctx, h0, inp2bf);

    // gates = [emb|ctx|h0] @ [W_ih | W_hh]^T  (K = 2048 + 1024)
    {
        dim3 g(32, 8);
        kskinny<<<g, 256, 0, stream>>>(inp2bf, 3072, W_ih, 2048, W_hh, gparts, 4096, 384);
    }
    klstm<<<256, 256, 0, stream>>>(gparts, b_ih, b_hh, c0, h1bf);

    // logits = h1 @ W_clf^T, K-split x2 for occupancy (500 blocks ~2/CU)
    {
        dim3 g(250, 2);
        kskinny<<<g, 256, 0, stream>>>(h1bf, 1024, W_clf, 1024, nullptr, lparts, 32000, 512);
    }
    klogsoftmax<<<64, 1024, 0, stream>>>(lparts, b_clf, out);
}

// Round 15
// 210.518 us; speedup vs baseline: 1.2191x; 1.2191x over previous
//
#include <hip/hip_runtime.h>
#include <hip/hip_bf16.h>
#include <math.h>

typedef unsigned short u16;
typedef unsigned int u32;
typedef __attribute__((ext_vector_type(4))) float f32x4;
typedef __attribute__((ext_vector_type(8))) short s16x8;
typedef __attribute__((ext_vector_type(8))) unsigned short u16x8;

#define DEV __device__ __forceinline__

// Problem dims: V=32000, E=1024, H=1024, A=1024, B=64, S=512

DEV u16 f2bf(float f) {
    union { float f; u32 u; } x{f};
    return (u16)((x.u + 0x7FFFu + ((x.u >> 16) & 1u)) >> 16);
}
DEV float bf2f(u16 h) {
    union { u32 u; float f; } x;
    x.u = ((u32)h) << 16;
    return x.f;
}
DEV float sigm(float x) { return 1.0f / (1.0f + __expf(-x)); }
DEV float tanh_f(float x) {
    float c = fminf(fmaxf(x, -9.0f), 9.0f);
    float e = __expf(2.0f * c);
    return (e - 1.0f) / (e + 1.0f);
}

// async global->LDS, 16B per lane (dest = wave-uniform base + lane*16)
#define GLL16(g, l) __builtin_amdgcn_global_load_lds( \
    (const __attribute__((address_space(1))) u32*)(g), \
    (__attribute__((address_space(3))) u32*)(l), 16, 0, 0)

// ------------------------- fused prep: cvt enc + zero scores + cvt Ua + h0
__global__ __launch_bounds__(256) void kprepcvt(
    const float* __restrict__ enc, const float* __restrict__ Ua,
    const float* __restrict__ h0, u16* __restrict__ encbf,
    u16* __restrict__ Uabf, u16* __restrict__ h0bf, float* __restrict__ scores)
{
    int bid = blockIdx.x, t = threadIdx.x;
    if (bid < 16384) {
        int i = bid * 256 + t;             // enc: 4194304 groups of 8
        float4 f0 = ((const float4*)enc)[i * 2];
        float4 f1 = ((const float4*)enc)[i * 2 + 1];
        u16x8 o = {f2bf(f0.x), f2bf(f0.y), f2bf(f0.z), f2bf(f0.w),
                   f2bf(f1.x), f2bf(f1.y), f2bf(f1.z), f2bf(f1.w)};
        ((u16x8*)encbf)[i] = o;
    } else if (bid < 16400) {
        int i = (bid - 16384) * 2048 + t * 8;   // scores zero (32768 f32)
        *(float4*)(scores + i) = (float4){0.f, 0.f, 0.f, 0.f};
        *(float4*)(scores + i + 4) = (float4){0.f, 0.f, 0.f, 0.f};
    } else if (bid < 16912) {
        int i = (bid - 16400) * 256 + t;   // Ua: 131072 groups of 8
        float4 f0 = ((const float4*)Ua)[i * 2];
        float4 f1 = ((const float4*)Ua)[i * 2 + 1];
        u16x8 o = {f2bf(f0.x), f2bf(f0.y), f2bf(f0.z), f2bf(f0.w),
                   f2bf(f1.x), f2bf(f1.y), f2bf(f1.z), f2bf(f1.w)};
        ((u16x8*)Uabf)[i] = o;
    } else {
        int i = (bid - 16912) * 256 + t;   // h0: 8192 groups of 8
        float4 f0 = ((const float4*)h0)[i * 2];
        float4 f1 = ((const float4*)h0)[i * 2 + 1];
        u16x8 o = {f2bf(f0.x), f2bf(f0.y), f2bf(f0.z), f2bf(f0.w),
                   f2bf(f1.x), f2bf(f1.y), f2bf(f1.z), f2bf(f1.w)};
        ((u16x8*)h0bf)[i] = o;
    }
}

// ------------------------------------------------- scores GEMM (the big one)
// scores[m] = sum_a va[a]*tanh(tmp1c[m&63][a] + sum_h enc[m,h]*Ua[a,h])
// M=32768, N=1024, K=1024 bf16.  256x256 tile, BK=64, 512 thr (2M x 4N
// waves), 2 LDS slots, counted vmcnt(6) once per K-tile, XOR swizzle via
// pre-swizzled global source, minimal-barrier schedule (3 bars/K-tile),
// compile-time tail flags (no dead prefetches).

template<int F0>
DEV void mmq(f32x4 (&acc)[8][4], const s16x8 (&af)[2][2], const s16x8 (&bfrag)[4][2]) {
#pragma unroll
    for (int f = 0; f < 2; f++)
#pragma unroll
        for (int j = 0; j < 4; j++) {
            acc[F0 + f][j] = __builtin_amdgcn_mfma_f32_16x16x32_bf16(af[f][0], bfrag[j][0], acc[F0 + f][j], 0, 0, 0);
            acc[F0 + f][j] = __builtin_amdgcn_mfma_f32_16x16x32_bf16(af[f][1], bfrag[j][1], acc[F0 + f][j], 0, 0, 0);
        }
}

__global__ __launch_bounds__(512, 1) void kscores256v2(
    const u16* __restrict__ encbf, const u16* __restrict__ Uabf,
    const float* __restrict__ tmp1c, const float* __restrict__ va,
    float* __restrict__ scores)
{
    // 2 slots x 64KB: slot s at elems s*32768; A rows [0,256) then B rows.
    __shared__ __align__(16) u16 shm[65536];   // 128 KB

    // XCD swizzle: 512 blocks / 8 XCDs -> 16 consecutive mt per XCD.
    int wg  = blockIdx.x;
    int lin = (wg & 7) * 64 + (wg >> 3);
    int mt  = lin >> 2, nt = lin & 3;   // mt 0..127, nt 0..3

    int t = threadIdx.x;
    int wid = t >> 6, lane = t & 63;
    int wm = wid >> 2, wn = wid & 3;    // 2M x 4N waves; per-wave out 128x64
    int lr = lane & 15, lg = lane >> 4;

    f32x4 acc[8][4];
#pragma unroll
    for (int i = 0; i < 8; i++)
#pragma unroll
        for (int j = 0; j < 4; j++) acc[i][j] = (f32x4){0.f, 0.f, 0.f, 0.f};

    // staging: one GLL16 line = 512 thr x 16B = 64 rows x 128B
    int srow = t >> 3;
    int sq8  = ((t & 7) ^ (srow & 7)) * 8;      // pre-swizzled source offset
    const u16* asrcb = encbf + (size_t)(mt * 256 + srow) * 1024 + sq8;
    const u16* bsrcb = Uabf + (size_t)(nt * 256 + srow) * 1024 + sq8;

#define STG_A(SE, RB, KO) GLL16(asrcb + (size_t)(RB) * 1024 + (KO), shm + (SE) + (RB) * 64 + t * 8)
#define STG_B(SE, RB, KO) GLL16(bsrcb + (size_t)(RB) * 1024 + (KO), shm + (SE) + 16384 + (RB) * 64 + t * 8)

    // per-lane read bases; swizzle inverse on read: q_read = q_want ^ (lr&7)
    const u16* Abase = shm + (wm * 128 + lr) * 64;
    const u16* Bbase = shm + 16384 + (wn * 64 + lr) * 64;
    int xor8 = (lr & 7) * 8;
    int o0 = (lg * 8) ^ xor8;            // ks=0
    int o1 = (32 + lg * 8) ^ xor8;       // ks=1

    s16x8 af[2][2], bfrag[4][2];

#define RD_A2(F0, AB) { \
    af[0][0] = *(const s16x8*)((AB) + (F0) * 1024 + o0); \
    af[0][1] = *(const s16x8*)((AB) + (F0) * 1024 + o1); \
    af[1][0] = *(const s16x8*)((AB) + (F0 + 1) * 1024 + o0); \
    af[1][1] = *(const s16x8*)((AB) + (F0 + 1) * 1024 + o1); }

#define MM(F0) \
    __builtin_amdgcn_s_setprio(1); \
    mmq<F0>(acc, af, bfrag); \
    __builtin_amdgcn_s_setprio(0);

#define BAR() \
    __builtin_amdgcn_s_barrier(); \
    __builtin_amdgcn_sched_barrier(0);

    // prologue: stage tiles 0,1 (order matches steady-state FIFO analysis)
    STG_B(0, 0, 0);  STG_B(0, 64, 0);  STG_B(0, 128, 0); STG_B(0, 192, 0);
    STG_A(0, 0, 0);  STG_A(0, 128, 0); STG_A(0, 64, 0);  STG_A(0, 192, 0);
    STG_B(32768, 0, 64);  STG_B(32768, 64, 64);
    STG_B(32768, 128, 64); STG_B(32768, 192, 64);
    STG_A(32768, 0, 64);  STG_A(32768, 128, 64);
    asm volatile("s_waitcnt vmcnt(6)" ::: "memory");   // tile0's 8 landed
    BAR();

// SAH: stage A-hi of T+1 (ph0); STP2: stage tile T+2 (ph1-3);
// WC: 6 = counted, 0 = full drain (tail), -1 = none.
#define TILE_BODY(T, SB, SBX, SAH, STP2, WC) { \
    int kA = (T) * 64 + 128; \
    int kH = (T) * 64 + 64; \
    const u16* Ab = Abase + (SB); \
    const u16* Bb = Bbase + (SB); \
    /* ph0: stage A-hi(T+1)->other slot; read all B-frags + A fi0,1 */ \
    if (SAH) { STG_A((SBX), 64, kH); STG_A((SBX), 192, kH); } \
    _Pragma("unroll") \
    for (int j = 0; j < 4; j++) { \
        bfrag[j][0] = *(const s16x8*)(Bb + j * 1024 + o0); \
        bfrag[j][1] = *(const s16x8*)(Bb + j * 1024 + o1); \
    } \
    RD_A2(0, Ab); \
    MM(0); \
    BAR();                      /* B-region reads complete everywhere */ \
    /* ph1: stage B-lo(T+2); A fi2,3 (no barrier — drift allowed) */ \
    if (STP2) { STG_B((SB), 0, kA); STG_B((SB), 64, kA); } \
    RD_A2(2, Ab); \
    MM(2); \
    __builtin_amdgcn_sched_barrier(0); \
    /* ph2: stage B-hi(T+2); A fi4,5 */ \
    if (STP2) { STG_B((SB), 128, kA); STG_B((SB), 192, kA); } \
    RD_A2(4, Ab); \
    MM(4); \
    BAR();                      /* A-lo reads (ph0/ph1) complete everywhere */ \
    /* ph3: stage A-lo(T+2); A fi6,7; tile-swap guard */ \
    if (STP2) { STG_A((SB), 0, kA); STG_A((SB), 128, kA); } \
    RD_A2(6, Ab); \
    if ((WC) == 6) { asm volatile("s_waitcnt vmcnt(6)" ::: "memory"); } \
    else if ((WC) == 0) { asm volatile("s_waitcnt vmcnt(0)" ::: "memory"); } \
    MM(6); \
    BAR();                      /* tile T+1 fully landed for next ph0 */ \
}

    for (int tt = 0; tt < 7; tt++) {
        int T0 = tt * 2;
        TILE_BODY(T0, 0, 32768, 1, 1, 6);
        TILE_BODY(T0 + 1, 32768, 0, 1, 1, 6);
    }
    // tail: T=14 stages only A-hi(15) at ph0, then drains; T=15 pure compute
    TILE_BODY(14, 0, 32768, 1, 0, 0);
    TILE_BODY(15, 32768, 0, 0, 0, -1);

    // stage tmp1c slice [64 b][256 a] into LDS, padded stride 260 f32
    float* ltmp = (float*)shm;
#pragma unroll
    for (int i = 0; i < 8; i++) {
        int idx = t + i * 512;              // 0..4095
        int row = idx >> 6, c4 = idx & 63;
        float4 v = *(const float4*)(tmp1c + row * 1024 + nt * 256 + c4 * 4);
        *(float4*)(ltmp + row * 260 + c4 * 4) = v;
    }
    __syncthreads();

    // Epilogue: val = va[a]*tanh(acc + tmp1[b][a]); reduce over this block's
    // 256 cols (4 n-waves x 64), atomicAdd per-row partial into scores.
    float vaj[4];
#pragma unroll
    for (int j = 0; j < 4; j++) vaj[j] = va[nt * 256 + wn * 64 + j * 16 + lr];

#pragma unroll
    for (int fi = 0; fi < 8; fi++) {
        float rs[4] = {0.f, 0.f, 0.f, 0.f};
#pragma unroll
        for (int j = 0; j < 4; j++) {
            int ac = wn * 64 + j * 16 + lr;
#pragma unroll
            for (int r = 0; r < 4; r++) {
                int b = (fi * 16 + lg * 4 + r) & 63;
                rs[r] += vaj[j] * tanh_f(acc[fi][j][r] + ltmp[b * 260 + ac]);
            }
        }
#pragma unroll
        for (int m = 1; m < 16; m <<= 1)
#pragma unroll
            for (int r = 0; r < 4; r++) rs[r] += __shfl_xor(rs[r], m, 64);
        if (lr == 0) {
            int mrow = mt * 256 + wm * 128 + fi * 16 + lg * 4;
#pragma unroll
            for (int r = 0; r < 4; r++) atomicAdd(&scores[mrow + r], rs[r]);
        }
    }
#undef STG_A
#undef STG_B
#undef RD_A2
#undef MM
#undef BAR
#undef TILE_BODY
}

// -------------------------------------- skinny GEMM: C = Abf(64xK) * B^T
// B is fp32 [N][K] split as [B1 (K1 cols) | B2 (K-K1 cols)], converted on the
// fly. Grid: (N/128, KS). Each block: 64x128 tile, 4 waves of 64x32.
__global__ __launch_bounds__(256) void kskinny(
    const u16* __restrict__ Abf, int Ktot,
    const float* __restrict__ B1, int K1,
    const float* __restrict__ B2,
    float* __restrict__ Cout, int N, int klen)
{
    __shared__ u16 As[64 * 40];
    __shared__ u16 Bs[128 * 40];

    int nt = blockIdx.x, p = blockIdx.y;
    int t = threadIdx.x;
    int wid = t >> 6, lane = t & 63;
    int lr = lane & 15, lg = lane >> 4;
    int K2 = Ktot - K1;

    f32x4 acc[4][2];
#pragma unroll
    for (int i = 0; i < 4; i++)
#pragma unroll
        for (int j = 0; j < 2; j++) acc[i][j] = (f32x4){0.f, 0.f, 0.f, 0.f};

    int arow = t >> 2, aq = t & 3;
    const u16* ap = Abf + (size_t)arow * Ktot + aq * 8;
    u16* asw = &As[arow * 40 + aq * 8];

    int brow = t >> 1, bhalf = t & 1;
    int n = nt * 128 + brow;
    u16* bsw = &Bs[brow * 40 + bhalf * 16];

    int kbeg = p * klen, kend = kbeg + klen;
    for (int k0 = kbeg; k0 < kend; k0 += 32) {
        __syncthreads();
        *(uint4*)asw = *(const uint4*)(ap + k0);
        int kk = k0 + bhalf * 16;
        const float* bp = (kk < K1) ? (B1 + (size_t)n * K1 + kk)
                                    : (B2 + (size_t)n * K2 + (kk - K1));
        float4 b0 = ((const float4*)bp)[0];
        float4 b1 = ((const float4*)bp)[1];
        float4 b2 = ((const float4*)bp)[2];
        float4 b3 = ((const float4*)bp)[3];
        u16x8 q0 = {f2bf(b0.x), f2bf(b0.y), f2bf(b0.z), f2bf(b0.w),
                    f2bf(b1.x), f2bf(b1.y), f2bf(b1.z), f2bf(b1.w)};
        u16x8 q1 = {f2bf(b2.x), f2bf(b2.y), f2bf(b2.z), f2bf(b2.w),
                    f2bf(b3.x), f2bf(b3.y), f2bf(b3.z), f2bf(b3.w)};
        *(u16x8*)bsw = q0;
        *(u16x8*)(bsw + 8) = q1;
        __syncthreads();

        const u16* abase = &As[lr * 40 + lg * 8];
        const u16* bbase = &Bs[(wid * 32 + lr) * 40 + lg * 8];
        s16x8 af[4], bfr[2];
#pragma unroll
        for (int i = 0; i < 4; i++) af[i]  = *(const s16x8*)(abase + i * 16 * 40);
#pragma unroll
        for (int j = 0; j < 2; j++) bfr[j] = *(const s16x8*)(bbase + j * 16 * 40);
#pragma unroll
        for (int i = 0; i < 4; i++)
#pragma unroll
            for (int j = 0; j < 2; j++)
                acc[i][j] = __builtin_amdgcn_mfma_f32_16x16x32_bf16(af[i], bfr[j], acc[i][j], 0, 0, 0);
    }

#pragma unroll
    for (int i = 0; i < 4; i++)
#pragma unroll
        for (int j = 0; j < 2; j++) {
            int m = i * 16 + lg * 4;
            int col = nt * 128 + wid * 32 + j * 16 + lr;
#pragma unroll
            for (int r = 0; r < 4; r++)
                Cout[((size_t)(p * 64 + m + r)) * N + col] = acc[i][j][r];
        }
}

// --------------------------------------------- reduce K-splits + add biases
__global__ void kredbias(const float* __restrict__ part, const float* __restrict__ bias1,
                         const float* __restrict__ bias2, float* __restrict__ out,
                         int N, int P)
{
    int idx = blockIdx.x * blockDim.x + threadIdx.x;
    if (idx >= 64 * N) return;
    int n = idx % N;
    float v = bias1[n] + bias2[n];
    for (int p = 0; p < P; p++) v += part[(size_t)p * 64 * N + idx];
    out[idx] = v;
}

// ---------------- ctx partial with fused softmax: 8 s-chunks x 64 b blocks
// Each block recomputes the softmax over S for its b column (2 KB, L2-hot),
// then does its chunk's weighted encoder sum — removes ksoftmax_w + wbuf.
__global__ __launch_bounds__(256) void kctx(const u16* __restrict__ encbf,
                                            const float* __restrict__ scores,
                                            float* __restrict__ pctx)
{
    int b = blockIdx.x & 63, ch = blockIdx.x >> 6;
    int t = threadIdx.x;
    int lane = t & 63, wv = t >> 6;
    __shared__ float redm[4], reds[4];
    __shared__ float wch[64];

    float v0 = scores[(2 * t) * 64 + b];
    float v1 = scores[(2 * t + 1) * 64 + b];
    float m = fmaxf(v0, v1);
#pragma unroll
    for (int mask = 1; mask < 64; mask <<= 1) m = fmaxf(m, __shfl_xor(m, mask, 64));
    if (lane == 0) redm[wv] = m;
    __syncthreads();
    m = fmaxf(fmaxf(redm[0], redm[1]), fmaxf(redm[2], redm[3]));
    float e0 = __expf(v0 - m), e1 = __expf(v1 - m);
    float sum = e0 + e1;
#pragma unroll
    for (int mask = 1; mask < 64; mask <<= 1) sum += __shfl_xor(sum, mask, 64);
    if (lane == 0) reds[wv] = sum;
    __syncthreads();
    sum = (reds[0] + reds[1]) + (reds[2] + reds[3]);
    float inv = 1.0f / sum;
    int base = ch * 32;
    if (t >= base && t < base + 32) {
        wch[2 * (t - base)]     = e0 * inv;
        wch[2 * (t - base) + 1] = e1 * inv;
    }
    __syncthreads();

    float4 acc = {0.f, 0.f, 0.f, 0.f};
    int s0 = ch * 64;
#pragma unroll 4
    for (int si = 0; si < 64; si++) {
        int s = s0 + si;
        float wv2 = wch[si];
        ushort4 e = ((const ushort4*)(encbf + ((size_t)(s * 64 + b)) * 1024))[t];
        acc.x += wv2 * bf2f(e.x); acc.y += wv2 * bf2f(e.y);
        acc.z += wv2 * bf2f(e.z); acc.w += wv2 * bf2f(e.w);
    }
    ((float4*)pctx)[((size_t)(ch * 64 + b)) * 256 + t] = acc;
}

// ---------------------- assemble LSTM input [emb[x] | ctx | h0] as bf16 rows
__global__ void kbuild(const int* __restrict__ x, const float* __restrict__ emb,
                       const float* __restrict__ pctx, const float* __restrict__ h0,
                       u16* __restrict__ inp2bf)
{
    int idx = blockIdx.x * blockDim.x + threadIdx.x;
    if (idx >= 64 * 3072) return;
    int b = idx / 3072, k = idx % 3072;
    float v;
    if (k < 1024) {
        v = emb[(size_t)x[b] * 1024 + k];
    } else if (k < 2048) {
        int h = k - 1024;
        v = 0.f;
        for (int p = 0; p < 8; p++) v += pctx[(size_t)(p * 64 + b) * 1024 + h];
    } else {
        v = h0[b * 1024 + (k - 2048)];
    }
    inp2bf[idx] = f2bf(v);
}

// --------------------------------------- reduce gate K-splits + LSTM step
__global__ void klstm(const float* __restrict__ gp, const float* __restrict__ b_ih,
                      const float* __restrict__ b_hh, const float* __restrict__ c0,
                      u16* __restrict__ h1bf)
{
    int idx = blockIdx.x * blockDim.x + threadIdx.x;  // 64*1024
    int b = idx >> 10, j = idx & 1023;
    float ig = b_ih[j] + b_hh[j];
    float fg = b_ih[1024 + j] + b_hh[1024 + j];
    float gg = b_ih[2048 + j] + b_hh[2048 + j];
    float og = b_ih[3072 + j] + b_hh[3072 + j];
    for (int p = 0; p < 8; p++) {
        const float* g = gp + ((size_t)p * 64 + b) * 4096;
        ig += g[j]; fg += g[1024 + j]; gg += g[2048 + j]; og += g[3072 + j];
    }
    float c = sigm(fg) * c0[idx] + sigm(ig) * tanh_f(gg);
    float h = sigm(og) * tanh_f(c);
    h1bf[idx] = f2bf(h);
}

// --------------- log-softmax (sums 2 logits K-split partials)
__global__ __launch_bounds__(1024) void klogsoftmax(const float* __restrict__ lp,
                                                    const float* __restrict__ b_clf,
                                                    float* __restrict__ out)
{
    int b = blockIdx.x, t = threadIdx.x;
    __shared__ float red[16], red2[16];
    float v[32];
    float mx = -1e30f;
#pragma unroll
    for (int i = 0; i < 32; i++) {
        int idx = t + i * 1024;
        if (idx < 32000) {
            float s = b_clf[idx];
#pragma unroll
            for (int p = 0; p < 2; p++)
                s += lp[((size_t)(p * 64 + b)) * 32000 + idx];
            v[i] = s;
            mx = fmaxf(mx, v[i]);
        } else v[i] = -1e30f;
    }
#pragma unroll
    for (int mask = 1; mask < 64; mask <<= 1) mx = fmaxf(mx, __shfl_xor(mx, mask, 64));
    if ((t & 63) == 0) red[t >> 6] = mx;
    __syncthreads();
#pragma unroll
    for (int k = 0; k < 16; k++) mx = fmaxf(mx, red[k]);
    float s = 0.f;
#pragma unroll
    for (int i = 0; i < 32; i++) {
        int idx = t + i * 1024;
        if (idx < 32000) s += __expf(v[i] - mx);
    }
#pragma unroll
    for (int mask = 1; mask < 64; mask <<= 1) s += __shfl_xor(s, mask, 64);
    if ((t & 63) == 0) red2[t >> 6] = s;
    __syncthreads();
    s = 0.f;
#pragma unroll
    for (int k = 0; k < 16; k++) s += red2[k];
    float lse = mx + logf(s);
#pragma unroll
    for (int i = 0; i < 32; i++) {
        int idx = t + i * 1024;
        if (idx < 32000) out[(size_t)b * 32000 + idx] = v[i] - lse;
    }
}

// =========================================================================
extern "C" void kernel_launch(void* const* d_in, const int* in_sizes, int n_in,
                              void* d_out, int out_size, void* d_ws, size_t ws_size,
                              hipStream_t stream)
{
    const int*   x     = (const int*)d_in[0];
    const float* enc   = (const float*)d_in[1];
    const float* h0    = (const float*)d_in[2];
    const float* c0    = (const float*)d_in[3];
    const float* Wa    = (const float*)d_in[4];
    const float* b_wa  = (const float*)d_in[5];
    const float* Ua    = (const float*)d_in[6];
    const float* b_ua  = (const float*)d_in[7];
    const float* va    = (const float*)d_in[8];
    // d_in[9] = b_va: constant shift, cancels in softmax over S -> unused
    const float* emb   = (const float*)d_in[10];
    const float* W_ih  = (const float*)d_in[11];
    const float* W_hh  = (const float*)d_in[12];
    const float* b_ih  = (const float*)d_in[13];
    const float* b_hh  = (const float*)d_in[14];
    const float* W_clf = (const float*)d_in[15];
    const float* b_clf = (const float*)d_in[16];
    float* out = (float*)d_out;

    char* ws = (char*)d_ws;
    // encbf occupies [0, 64MB); gparts/lparts overlay it (used only after
    // kctx, the last encbf reader — launches are stream-ordered).
    u16*   encbf    = (u16*)  (ws + 0);           // 33.5M bf16 (64 MB)
    float* gparts   = (float*)(ws + 0);           // 8*64*4096 f32 (8 MB)
    float* lparts   = (float*)(ws + 8388608);     // 2*64*32000 f32 (16.4 MB)
    float* scores   = (float*)(ws + 67108864);    // 32768 f32
    float* tmp1part = (float*)(ws + 67371008);    // 8*64*1024 f32 (2 MB)
    float* tmp1c    = (float*)(ws + 69468160);    // 64*1024 f32 (256 KB)
    u16*   h0bf     = (u16*)  (ws + 69730304);    // 64*1024 bf16 (128 KB)
    u16*   Uabf     = (u16*)  (ws + 69861376);    // 1M bf16 (2 MB)
    float* pctx     = (float*)(ws + 71958528);    // 8*64*1024 f32 (2 MB)
    u16*   inp2bf   = (u16*)  (ws + 74055680);    // 64*3072 bf16 (384 KB)
    u16*   h1bf     = (u16*)  (ws + 74448896);    // 64*1024 bf16 (128 KB)
    // total ~74.6 MB

    kprepcvt<<<16944, 256, 0, stream>>>(enc, Ua, h0, encbf, Uabf, h0bf, scores);

    // tmp1[b][a] = h0 . Wa[a]  (+ b_wa + b_ua in reduce)
    {
        dim3 g(8, 8);
        kskinny<<<g, 256, 0, stream>>>(h0bf, 1024, Wa, 1024, nullptr, tmp1part, 1024, 128);
    }
    kredbias<<<256, 256, 0, stream>>>(tmp1part, b_wa, b_ua, tmp1c, 1024, 8);

    kscores256v2<<<512, 512, 0, stream>>>(encbf, Uabf, tmp1c, va, scores);
    kctx<<<512, 256, 0, stream>>>(encbf, scores, pctx);
    kbuild<<<768, 256, 0, stream>>>(x, emb, pctx, h0, inp2bf);

    // gates = [emb|ctx|h0] @ [W_ih | W_hh]^T  (K = 2048 + 1024)
    {
        dim3 g(32, 8);
        kskinny<<<g, 256, 0, stream>>>(inp2bf, 3072, W_ih, 2048, W_hh, gparts, 4096, 384);
    }
    klstm<<<256, 256, 0, stream>>>(gparts, b_ih, b_hh, c0, h1bf);

    // logits = h1 @ W_clf^T, K-split x2 for occupancy (500 blocks ~2/CU)
    {
        dim3 g(250, 2);
        kskinny<<<g, 256, 0, stream>>>(h1bf, 1024, W_clf, 1024, nullptr, lparts, 32000, 512);
    }
    klogsoftmax<<<64, 1024, 0, stream>>>(lparts, b_clf, out);
}